// Round 11
// baseline (378.668 us; speedup 1.0000x reference)
//
#include <hip/hip_runtime.h>
#include <hip/hip_fp16.h>

#define N_NODES  100000
#define N_EDGES  1200000
#define N_GRAPHS 1024
#define F        64
#define BN_EPS   1e-5f
#define NBUCK    ((N_NODES + 255) / 256)       // 391 buckets of 256 node IDs
#define NCHUNK   NBUCK                          // one chunk per block (391)
#define CHUNK    ((N_EDGES + NCHUNK - 1) / NCHUNK) // 3070 edges per chunk
#define MT       128                            // GEMM nodes per block
#define GEMM_BLOCKS ((N_NODES + MT - 1) / MT)   // 782

// ---------------------------------------------------------------------------
// prep: dense GEMM Uh = feats@Wself, Zh = feats@Wneigh (fp16 out). Also zeroes
// hgbits and the grid-barrier state for csr_build (stream-ordered before it).
// ---------------------------------------------------------------------------
__global__ __launch_bounds__(256) void prep(
    const float* __restrict__ feats, const float* __restrict__ Wself,
    const float* __restrict__ Wneigh, __half* __restrict__ Uh,
    __half* __restrict__ Zh, int* __restrict__ hgbits, int* __restrict__ bar) {
  __shared__ float As[MT * 65];
  __shared__ float Ws[64 * 128];
  int t = threadIdx.x;
  int zidx = blockIdx.x * 256 + t;
  if (zidx < N_GRAPHS * F) hgbits[zidx] = 0;
  if (blockIdx.x == 0 && t < 2) bar[t] = 0;

  int mbase = blockIdx.x * MT;
  for (int i = t; i < 64 * 128; i += 256) {
    int k = i >> 7, j = i & 127;
    Ws[i] = (j < 64) ? Wself[k * 64 + j] : Wneigh[k * 64 + (j - 64)];
  }
#pragma unroll
  for (int s = 0; s < 8; s++) {
    int idx = (s * 256 + t) * 4;
    int m = idx >> 6, k = idx & 63;
    int gm = mbase + m;
    float4 v = (gm < N_NODES) ? *(const float4*)(feats + (size_t)gm * F + k)
                              : make_float4(0.f, 0.f, 0.f, 0.f);
    float* d = As + m * 65 + k;
    d[0] = v.x; d[1] = v.y; d[2] = v.z; d[3] = v.w;
  }
  __syncthreads();

  int wave = t >> 6, lane = t & 63;
  int jq = lane & 3, nq = lane >> 2;
  int half = wave & 1;
  int mb = (wave >> 1) * 64 + 4 * nq;
  int joff = half * 64 + jq * 16;

  float acc[4][16];
#pragma unroll
  for (int i = 0; i < 4; i++)
#pragma unroll
    for (int c = 0; c < 16; c++) acc[i][c] = 0.f;

#pragma unroll 4
  for (int k = 0; k < 64; k++) {
    float a0 = As[(mb + 0) * 65 + k];
    float a1 = As[(mb + 1) * 65 + k];
    float a2 = As[(mb + 2) * 65 + k];
    float a3 = As[(mb + 3) * 65 + k];
    const float4* wr = (const float4*)(Ws + k * 128 + joff);
    float4 w4[4];
    w4[0] = wr[0]; w4[1] = wr[1]; w4[2] = wr[2]; w4[3] = wr[3];
    const float* w = (const float*)w4;
#pragma unroll
    for (int c = 0; c < 16; c++) {
      float wv = w[c];
      acc[0][c] += a0 * wv;
      acc[1][c] += a1 * wv;
      acc[2][c] += a2 * wv;
      acc[3][c] += a3 * wv;
    }
  }

  __half* outp = half ? Zh : Uh;
  int jbase = jq * 16;
#pragma unroll
  for (int i = 0; i < 4; i++) {
    int gm = mbase + mb + i;
    if (gm < N_NODES) {
#pragma unroll
      for (int c4 = 0; c4 < 4; c4++) {
        union { __half h[4]; uint2 u; } pk;
        pk.h[0] = __float2half_rn(acc[i][c4 * 4 + 0]);
        pk.h[1] = __float2half_rn(acc[i][c4 * 4 + 1]);
        pk.h[2] = __float2half_rn(acc[i][c4 * 4 + 2]);
        pk.h[3] = __float2half_rn(acc[i][c4 * 4 + 3]);
        *(uint2*)(outp + (size_t)gm * F + jbase + c4 * 4) = pk.u;
      }
    }
  }
}

// ---------------------------------------------------------------------------
// Device-scope grid barrier (counter + generation). 391 blocks << 2048-block
// residency capacity -> spin is live. __threadfence release/acquire makes
// phase writes visible across XCD L2s (G16 mechanism).
// ---------------------------------------------------------------------------
__device__ __forceinline__ void gridbar(int* cnt, int* gen, int nblk) {
  __syncthreads();
  if (threadIdx.x == 0) {
    __threadfence();                                 // release
    int g = atomicAdd(gen, 0);
    if (atomicAdd(cnt, 1) == nblk - 1) {
      atomicExch(cnt, 0);
      __threadfence();
      atomicAdd(gen, 1);
    } else {
      while (atomicAdd(gen, 0) == g) __builtin_amdgcn_s_sleep(8);
    }
    __threadfence();                                 // acquire
  }
  __syncthreads();
}

// ---------------------------------------------------------------------------
// csr_build: ALL of [chist -> cscan -> bscan -> cscat -> place] in ONE launch
// (391 blocks x 256). Replaces 5 kernels; removes 4 inter-dispatch drains.
// ---------------------------------------------------------------------------
__global__ __launch_bounds__(256) void csr_build(
    const int* __restrict__ src, const int* __restrict__ dst,
    int* __restrict__ Ct, int* __restrict__ bcnt, int* __restrict__ bstart,
    int* __restrict__ pairs, int* __restrict__ rs, int* __restrict__ eidx,
    int* __restrict__ bar) {
  __shared__ int sm[512];
  int b = blockIdx.x, t = threadIdx.x;
  int e0 = b * CHUNK, e1 = e0 + CHUNK;
  if (e1 > N_EDGES) e1 = N_EDGES;

  // ---- phase A: per-chunk bucket histogram (LDS int atomics) ----
  for (int i = t; i < NBUCK; i += 256) sm[i] = 0;
  __syncthreads();
  for (int e = e0 + t; e < e1; e += 256) atomicAdd(&sm[dst[e] >> 8], 1);
  __syncthreads();
  for (int i = t; i < NBUCK; i += 256) Ct[(size_t)b * NBUCK + i] = sm[i];
  gridbar(&bar[0], &bar[1], NCHUNK);

  // ---- phase B: per-bucket scan over chunk counts (bucket = b) ----
  {
    int c0 = 2 * t, c1 = 2 * t + 1;
    int x0 = (c0 < NCHUNK) ? Ct[(size_t)c0 * NBUCK + b] : 0;
    int x1 = (c1 < NCHUNK) ? Ct[(size_t)c1 * NBUCK + b] : 0;
    int s = x0 + x1;
    sm[t] = s;
    __syncthreads();
    for (int off = 1; off < 256; off <<= 1) {
      int u = (t >= off) ? sm[t - off] : 0;
      __syncthreads();
      sm[t] += u;
      __syncthreads();
    }
    int excl = sm[t] - s;
    if (c0 < NCHUNK) Ct[(size_t)c0 * NBUCK + b] = excl;
    if (c1 < NCHUNK) Ct[(size_t)c1 * NBUCK + b] = excl + x0;
    if (t == 255) bcnt[b] = sm[255];                 // bucket total
  }
  gridbar(&bar[0], &bar[1], NCHUNK);

  // ---- phase C: block 0 scans bucket totals -> bstart ----
  if (b == 0) {
    int c0 = 2 * t, c1 = 2 * t + 1;
    int x0 = (c0 < NBUCK) ? atomicAdd(&bcnt[c0], 0) : 0;
    int x1 = (c1 < NBUCK) ? atomicAdd(&bcnt[c1], 0) : 0;
    int s = x0 + x1;
    sm[t] = s;
    __syncthreads();
    for (int off = 1; off < 256; off <<= 1) {
      int u = (t >= off) ? sm[t - off] : 0;
      __syncthreads();
      sm[t] += u;
      __syncthreads();
    }
    int excl = sm[t] - s;
    if (c0 < NBUCK) bstart[c0] = excl;
    if (c1 < NBUCK) bstart[c1] = excl + x0;
    if (t == 0) bstart[NBUCK] = N_EDGES;
  }
  gridbar(&bar[0], &bar[1], NCHUNK);

  // ---- phase D: deterministic scatter of packed (local_dst<<24 | src) ----
  for (int i = t; i < NBUCK; i += 256)
    sm[i] = bstart[i] + Ct[(size_t)b * NBUCK + i];
  __syncthreads();
  for (int e = e0 + t; e < e1; e += 256) {
    int d = dst[e];
    int pos = atomicAdd(&sm[d >> 8], 1);
    pairs[pos] = (int)((((unsigned)d & 255u) << 24) | (unsigned)src[e]);
  }
  gridbar(&bar[0], &bar[1], NCHUNK);

  // ---- phase E: per-bucket place (bucket = b): rs + sorted eidx ----
  {
    int* lh  = sm;          // [256]
    int* cur = sm + 256;    // [256]
    int nb0 = b << 8;
    int r0 = bstart[b], r1 = bstart[b + 1];

    lh[t] = 0;
    __syncthreads();
    for (int e = r0 + t; e < r1; e += 256)
      atomicAdd(&lh[((unsigned)pairs[e]) >> 24], 1);
    __syncthreads();

    int v = lh[t];
    cur[t] = v;
    __syncthreads();
    for (int off = 1; off < 256; off <<= 1) {
      int u = (t >= off) ? cur[t - off] : 0;
      __syncthreads();
      cur[t] += u;
      __syncthreads();
    }
    int excl = cur[t] - v;
    int node = nb0 + t;
    if (node < N_NODES) rs[node] = r0 + excl;
    if (b == 0 && t == 0) rs[N_NODES] = N_EDGES;
    __syncthreads();
    cur[t] = r0 + excl;
    __syncthreads();

    for (int e = r0 + t; e < r1; e += 256) {
      unsigned p = (unsigned)pairs[e];
      int pos = atomicAdd(&cur[p >> 24], 1);
      eidx[pos] = (int)(p & 0xFFFFFFu);
    }
  }
}

// ---------------------------------------------------------------------------
// Fused gather + SAGE update + ReLU + per-graph max readout (R8 v2, proven).
// Neighbor batches of 16: sub handles jj+sub+{0,4,8,12} -> 16 independent
// uint2 loads in flight per wave.
// ---------------------------------------------------------------------------
__global__ __launch_bounds__(256) void gather_h(
    const __half* __restrict__ Uh, const __half* __restrict__ Zh,
    const int* __restrict__ rs, const int* __restrict__ eidx,
    const float* __restrict__ bneigh, const int* __restrict__ gids,
    int* __restrict__ hgbits) {
  int lane = threadIdx.x & 63;
  int wid  = (blockIdx.x * blockDim.x + threadIdx.x) >> 6;
  const int NW = (2048 * 256) >> 6;                 // 8192 waves
  const int per = (N_NODES + NW - 1) / NW;          // 13 nodes/wave
  int n0 = wid * per;
  int n1 = n0 + per; if (n1 > N_NODES) n1 = N_NODES;
  if (n0 >= n1) return;
  int fl  = lane & 15;
  int sub = lane >> 4;
  float4 b4 = *(const float4*)(bneigh + 4 * fl);

  int curg = gids[n0];
  float4 gmax = {0.f, 0.f, 0.f, 0.f};

  for (int n = n0; n < n1; n++) {
    uint2 ur = *(const uint2*)(Uh + (size_t)n * F + 4 * fl);
    int r0 = rs[n], r1 = rs[n + 1];
    float sx = 0.f, sy = 0.f, sz = 0.f, sw = 0.f;
    for (int base = r0; base < r1; base += 64) {
      int m = r1 - base; if (m > 64) m = 64;
      int myid = (lane < m) ? eidx[base + lane] : 0;
      for (int jj = 0; jj < m; jj += 16) {
        int j0 = jj + sub;
        int s0 = __shfl(myid, j0);
        int s1 = __shfl(myid, j0 + 4);
        int s2 = __shfl(myid, j0 + 8);
        int s3 = __shfl(myid, j0 + 12);
        uint2 z0 = *(const uint2*)(Zh + (size_t)s0 * F + 4 * fl);
        uint2 z1 = *(const uint2*)(Zh + (size_t)s1 * F + 4 * fl);
        uint2 z2 = *(const uint2*)(Zh + (size_t)s2 * F + 4 * fl);
        uint2 z3 = *(const uint2*)(Zh + (size_t)s3 * F + 4 * fl);
        if (j0 < m) {
          float2 f0 = __half22float2(*(__half2*)&z0.x);
          float2 f1 = __half22float2(*(__half2*)&z0.y);
          sx += f0.x; sy += f0.y; sz += f1.x; sw += f1.y;
        }
        if (j0 + 4 < m) {
          float2 f0 = __half22float2(*(__half2*)&z1.x);
          float2 f1 = __half22float2(*(__half2*)&z1.y);
          sx += f0.x; sy += f0.y; sz += f1.x; sw += f1.y;
        }
        if (j0 + 8 < m) {
          float2 f0 = __half22float2(*(__half2*)&z2.x);
          float2 f1 = __half22float2(*(__half2*)&z2.y);
          sx += f0.x; sy += f0.y; sz += f1.x; sw += f1.y;
        }
        if (j0 + 12 < m) {
          float2 f0 = __half22float2(*(__half2*)&z3.x);
          float2 f1 = __half22float2(*(__half2*)&z3.y);
          sx += f0.x; sy += f0.y; sz += f1.x; sw += f1.y;
        }
      }
    }
    sx += __shfl_xor(sx, 16); sy += __shfl_xor(sy, 16);
    sz += __shfl_xor(sz, 16); sw += __shfl_xor(sw, 16);
    sx += __shfl_xor(sx, 32); sy += __shfl_xor(sy, 32);
    sz += __shfl_xor(sz, 32); sw += __shfl_xor(sw, 32);
    float inv = 1.0f / fmaxf((float)(r1 - r0), 1.0f);

    int g = gids[n];
    if (g != curg) {
      if (sub == 0) {
        int* hp = hgbits + (size_t)curg * F + 4 * fl;
        atomicMax(hp + 0, __float_as_int(gmax.x));
        atomicMax(hp + 1, __float_as_int(gmax.y));
        atomicMax(hp + 2, __float_as_int(gmax.z));
        atomicMax(hp + 3, __float_as_int(gmax.w));
      }
      curg = g; gmax = make_float4(0.f, 0.f, 0.f, 0.f);
    }

    float2 uf0 = __half22float2(*(__half2*)&ur.x);
    float2 uf1 = __half22float2(*(__half2*)&ur.y);
    gmax.x = fmaxf(gmax.x, fmaxf(uf0.x + sx * inv + b4.x, 0.f));
    gmax.y = fmaxf(gmax.y, fmaxf(uf0.y + sy * inv + b4.y, 0.f));
    gmax.z = fmaxf(gmax.z, fmaxf(uf1.x + sz * inv + b4.z, 0.f));
    gmax.w = fmaxf(gmax.w, fmaxf(uf1.y + sw * inv + b4.w, 0.f));
  }
  if (sub == 0) {
    int* hp = hgbits + (size_t)curg * F + 4 * fl;
    atomicMax(hp + 0, __float_as_int(gmax.x));
    atomicMax(hp + 1, __float_as_int(gmax.y));
    atomicMax(hp + 2, __float_as_int(gmax.z));
    atomicMax(hp + 3, __float_as_int(gmax.w));
  }
}

// ---------------------------------------------------------------------------
// MLP head: weights staged in LDS once, 8 graphs per block.
// ---------------------------------------------------------------------------
#define GPB 8
__global__ __launch_bounds__(128) void mlp(
    const float* __restrict__ hg,
    const float* __restrict__ W1, const float* __restrict__ b1,
    const float* __restrict__ g1, const float* __restrict__ be1,
    const float* __restrict__ rm1, const float* __restrict__ rv1,
    const float* __restrict__ W2, const float* __restrict__ b2,
    const float* __restrict__ g2, const float* __restrict__ be2,
    const float* __restrict__ rm2, const float* __restrict__ rv2,
    const float* __restrict__ W3, const float* __restrict__ b3,
    float* __restrict__ out) {
  __shared__ float W1s[64 * 128];
  __shared__ float W2s[128 * 64];
  __shared__ float W3s[64];
  __shared__ float sc1[128], sh1[128], b1s[128];
  __shared__ float sc2[64],  sh2[64],  b2s[64];
  __shared__ float s0[64], s1[128], s2[64];
  int t = threadIdx.x;

  for (int i = t; i < 64 * 128; i += 128) W1s[i] = W1[i];
  for (int i = t; i < 128 * 64; i += 128) W2s[i] = W2[i];
  if (t < 64) W3s[t] = W3[t];
  {
    float iv = rsqrtf(rv1[t] + BN_EPS);
    float sc = g1[t] * iv;
    sc1[t] = sc; sh1[t] = be1[t] - rm1[t] * sc; b1s[t] = b1[t];
  }
  if (t < 64) {
    float iv = rsqrtf(rv2[t] + BN_EPS);
    float sc = g2[t] * iv;
    sc2[t] = sc; sh2[t] = be2[t] - rm2[t] * sc; b2s[t] = b2[t];
  }
  __syncthreads();

  for (int gg = 0; gg < GPB; gg++) {
    int g = blockIdx.x * GPB + gg;
    if (t < 64) s0[t] = hg[(size_t)g * F + t];
    __syncthreads();
    {
      float acc = b1s[t];
      for (int i = 0; i < 64; i++) acc += s0[i] * W1s[i * 128 + t];
      acc = fmaxf(acc, 0.0f);
      s1[t] = acc * sc1[t] + sh1[t];
    }
    __syncthreads();
    if (t < 64) {
      float acc = b2s[t];
      for (int i = 0; i < 128; i++) acc += s1[i] * W2s[i * 64 + t];
      acc = fmaxf(acc, 0.0f);
      s2[t] = acc * sc2[t] + sh2[t];
    }
    __syncthreads();
    if (t < 64) {
      float p = s2[t] * W3s[t];
      for (int off = 32; off > 0; off >>= 1) p += __shfl_down(p, off);
      if (t == 0) out[g] = p + b3[0];
    }
    __syncthreads();
  }
}

// ---------------------------------------------------------------------------
extern "C" void kernel_launch(void* const* d_in, const int* in_sizes, int n_in,
                              void* d_out, int out_size, void* d_ws, size_t ws_size,
                              hipStream_t stream) {
  const float* feats  = (const float*)d_in[0];
  const int*   src    = (const int*)d_in[1];
  const int*   dst    = (const int*)d_in[2];
  const int*   gids   = (const int*)d_in[3];
  const float* Wself  = (const float*)d_in[4];
  const float* Wneigh = (const float*)d_in[5];
  const float* bneigh = (const float*)d_in[6];
  const float* W1  = (const float*)d_in[7];
  const float* b1  = (const float*)d_in[8];
  const float* g1  = (const float*)d_in[9];
  const float* be1 = (const float*)d_in[10];
  const float* rm1 = (const float*)d_in[11];
  const float* rv1 = (const float*)d_in[12];
  const float* W2  = (const float*)d_in[13];
  const float* b2  = (const float*)d_in[14];
  const float* g2  = (const float*)d_in[15];
  const float* be2 = (const float*)d_in[16];
  const float* rm2 = (const float*)d_in[17];
  const float* rv2 = (const float*)d_in[18];
  const float* W3  = (const float*)d_in[19];
  const float* b3  = (const float*)d_in[20];

  // ws layout: Uh | Zh | rs | bstart | bcnt | bar | hgbits | Ct | pairs | eidx
  __half* Uh   = (__half*)d_ws;                      // N_NODES*64 halves
  __half* Zh   = Uh + (size_t)N_NODES * F;           // N_NODES*64 halves
  int* rs      = (int*)(Zh + (size_t)N_NODES * F);   // N_NODES+1
  int* bstart  = rs + (N_NODES + 1);                 // NBUCK+1
  int* bcnt    = bstart + (NBUCK + 1);               // NBUCK
  int* bar     = bcnt + NBUCK;                       // 2 (zeroed in prep)
  int* hgbits  = bar + 2;                            // N_GRAPHS*F (zeroed in prep)
  int* Ct      = hgbits + (size_t)N_GRAPHS * F;      // NCHUNK*NBUCK
  int* pairs   = Ct + (size_t)NCHUNK * NBUCK;        // N_EDGES
  int* eidx    = pairs + N_EDGES;                    // N_EDGES

  prep<<<GEMM_BLOCKS, 256, 0, stream>>>(feats, Wself, Wneigh, Uh, Zh,
                                        hgbits, bar);
  csr_build<<<NCHUNK, 256, 0, stream>>>(src, dst, Ct, bcnt, bstart,
                                        pairs, rs, eidx, bar);
  gather_h<<<2048, 256, 0, stream>>>(Uh, Zh, rs, eidx, bneigh, gids, hgbits);
  mlp<<<N_GRAPHS / GPB, 128, 0, stream>>>((const float*)hgbits,
                                          W1, b1, g1, be1, rm1, rv1,
                                          W2, b2, g2, be2, rm2, rv2, W3, b3,
                                          (float*)d_out);
}

// Round 12
// 303.064 us; speedup vs baseline: 1.2495x; 1.2495x over previous
//
#include <hip/hip_runtime.h>
#include <hip/hip_fp16.h>

#define N_NODES  100000
#define N_EDGES  1200000
#define N_GRAPHS 1024
#define F        64
#define BN_EPS   1e-5f
#define NBUCK    ((N_NODES + 255) / 256)       // 391 buckets of 256 node IDs
#define NBLK     512                            // scatter chunks
#define CHUNK    ((N_EDGES + NBLK - 1) / NBLK)  // 2344 edges per chunk
#define MT       128                            // GEMM nodes per block
#define GEMM_BLOCKS ((N_NODES + MT - 1) / MT)   // 782

// ---------------------------------------------------------------------------
// prep: fused [gemm_uz | chist] (R10, measured-neutral, saves a launch).
// Also zeroes hgbits and the cscan2 done-counter.
// ---------------------------------------------------------------------------
__global__ __launch_bounds__(256) void prep(
    const float* __restrict__ feats, const float* __restrict__ Wself,
    const float* __restrict__ Wneigh, __half* __restrict__ Uh,
    __half* __restrict__ Zh, const int* __restrict__ dst,
    int* __restrict__ Ct, int* __restrict__ hgbits, int* __restrict__ done) {
  __shared__ __align__(16) char smraw[MT * 65 * 4 + 64 * 128 * 4];
  int t = threadIdx.x;
  if (blockIdx.x == 0 && t == 0) *done = 0;

  if (blockIdx.x >= GEMM_BLOCKS) {
    // ---- chist part ----
    int* lh = (int*)smraw;
    int b = blockIdx.x - GEMM_BLOCKS;
    int zidx = b * 256 + t;
    if (zidx < N_GRAPHS * F) hgbits[zidx] = 0;
    for (int i = t; i < NBUCK; i += 256) lh[i] = 0;
    __syncthreads();
    int e0 = b * CHUNK, e1 = e0 + CHUNK;
    if (e1 > N_EDGES) e1 = N_EDGES;
    for (int e = e0 + t; e < e1; e += 256) atomicAdd(&lh[dst[e] >> 8], 1);
    __syncthreads();
    for (int i = t; i < NBUCK; i += 256) Ct[(size_t)b * NBUCK + i] = lh[i];
    return;
  }

  // ---- GEMM part: Uh = feats@Wself, Zh = feats@Wneigh (fp16 out) ----
  float* As = (float*)smraw;                   // MT x 65
  float* Ws = (float*)(smraw + MT * 65 * 4);   // 64 x 128
  int mbase = blockIdx.x * MT;

  for (int i = t; i < 64 * 128; i += 256) {
    int k = i >> 7, j = i & 127;
    Ws[i] = (j < 64) ? Wself[k * 64 + j] : Wneigh[k * 64 + (j - 64)];
  }
#pragma unroll
  for (int s = 0; s < 8; s++) {
    int idx = (s * 256 + t) * 4;
    int m = idx >> 6, k = idx & 63;
    int gm = mbase + m;
    float4 v = (gm < N_NODES) ? *(const float4*)(feats + (size_t)gm * F + k)
                              : make_float4(0.f, 0.f, 0.f, 0.f);
    float* d = As + m * 65 + k;
    d[0] = v.x; d[1] = v.y; d[2] = v.z; d[3] = v.w;
  }
  __syncthreads();

  int wave = t >> 6, lane = t & 63;
  int jq = lane & 3, nq = lane >> 2;
  int half = wave & 1;
  int mb = (wave >> 1) * 64 + 4 * nq;
  int joff = half * 64 + jq * 16;

  float acc[4][16];
#pragma unroll
  for (int i = 0; i < 4; i++)
#pragma unroll
    for (int c = 0; c < 16; c++) acc[i][c] = 0.f;

#pragma unroll 4
  for (int k = 0; k < 64; k++) {
    float a0 = As[(mb + 0) * 65 + k];
    float a1 = As[(mb + 1) * 65 + k];
    float a2 = As[(mb + 2) * 65 + k];
    float a3 = As[(mb + 3) * 65 + k];
    const float4* wr = (const float4*)(Ws + k * 128 + joff);
    float4 w4[4];
    w4[0] = wr[0]; w4[1] = wr[1]; w4[2] = wr[2]; w4[3] = wr[3];
    const float* w = (const float*)w4;
#pragma unroll
    for (int c = 0; c < 16; c++) {
      float wv = w[c];
      acc[0][c] += a0 * wv;
      acc[1][c] += a1 * wv;
      acc[2][c] += a2 * wv;
      acc[3][c] += a3 * wv;
    }
  }

  __half* outp = half ? Zh : Uh;
  int jbase = jq * 16;
#pragma unroll
  for (int i = 0; i < 4; i++) {
    int gm = mbase + mb + i;
    if (gm < N_NODES) {
#pragma unroll
      for (int c4 = 0; c4 < 4; c4++) {
        union { __half h[4]; uint2 u; } pk;
        pk.h[0] = __float2half_rn(acc[i][c4 * 4 + 0]);
        pk.h[1] = __float2half_rn(acc[i][c4 * 4 + 1]);
        pk.h[2] = __float2half_rn(acc[i][c4 * 4 + 2]);
        pk.h[3] = __float2half_rn(acc[i][c4 * 4 + 3]);
        *(uint2*)(outp + (size_t)gm * F + jbase + c4 * 4) = pk.u;
      }
    }
  }
}

// ---------------------------------------------------------------------------
// cscan2: per-bucket scan over chunk counts; the LAST finishing block also
// scans bucket totals -> bstart (one pipelined atomicAdd per block, no spin).
// ---------------------------------------------------------------------------
__global__ __launch_bounds__(NBLK) void cscan2(int* __restrict__ Ct,
                                               int* __restrict__ bcnt,
                                               int* __restrict__ bstart,
                                               int* __restrict__ done) {
  __shared__ int s[NBLK];
  __shared__ int lastflag;
  int i = blockIdx.x, t = threadIdx.x;
  int v = Ct[(size_t)t * NBUCK + i];
  s[t] = v;
  __syncthreads();
  for (int off = 1; off < NBLK; off <<= 1) {
    int u = (t >= off) ? s[t - off] : 0;
    __syncthreads();
    s[t] += u;
    __syncthreads();
  }
  Ct[(size_t)t * NBUCK + i] = s[t] - v;
  if (t == NBLK - 1) bcnt[i] = s[NBLK - 1];
  __threadfence();          // release bcnt/Ct before signaling done
  __syncthreads();
  if (t == 0) lastflag = (atomicAdd(done, 1) == NBUCK - 1) ? 1 : 0;
  __syncthreads();
  if (!lastflag) return;

  // last block: scan the 391 bucket totals (acquire via atomicAdd(,0))
  int w = (t < NBUCK) ? atomicAdd(&bcnt[t], 0) : 0;
  s[t] = w;
  __syncthreads();
  for (int off = 1; off < NBLK; off <<= 1) {
    int u = (t >= off) ? s[t - off] : 0;
    __syncthreads();
    s[t] += u;
    __syncthreads();
  }
  if (t < NBUCK) bstart[t] = s[t] - w;
  if (t == 0) bstart[NBUCK] = N_EDGES;
}

// ---------------------------------------------------------------------------
// cscat: deterministic scatter of packed (local_dst<<24 | src) (proven).
// ---------------------------------------------------------------------------
__global__ __launch_bounds__(256) void cscat(const int* __restrict__ src,
                                             const int* __restrict__ dst,
                                             const int* __restrict__ Ct,
                                             const int* __restrict__ bstart,
                                             int* __restrict__ pairs) {
  __shared__ int cur[NBUCK];
  int b = blockIdx.x, t = threadIdx.x;
  for (int i = t; i < NBUCK; i += 256)
    cur[i] = bstart[i] + Ct[(size_t)b * NBUCK + i];
  __syncthreads();
  int e0 = b * CHUNK, e1 = e0 + CHUNK;
  if (e1 > N_EDGES) e1 = N_EDGES;
  for (int e = e0 + t; e < e1; e += 256) {
    int d = dst[e];
    int pos = atomicAdd(&cur[d >> 8], 1);
    pairs[pos] = (int)((((unsigned)d & 255u) << 24) | (unsigned)src[e]);
  }
}

// ---------------------------------------------------------------------------
// place: per-bucket rs + sorted eidx (proven).
// ---------------------------------------------------------------------------
__global__ __launch_bounds__(256) void place(const int* __restrict__ pairs,
                                             const int* __restrict__ bstart,
                                             int* __restrict__ rs,
                                             int* __restrict__ eidx) {
  __shared__ int lh[256];
  __shared__ int cur[256];
  int b = blockIdx.x, t = threadIdx.x;
  int nb0 = b << 8;
  int r0 = bstart[b], r1 = bstart[b + 1];

  lh[t] = 0;
  __syncthreads();
  for (int e = r0 + t; e < r1; e += 256)
    atomicAdd(&lh[((unsigned)pairs[e]) >> 24], 1);
  __syncthreads();

  int v = lh[t];
  cur[t] = v;
  __syncthreads();
  for (int off = 1; off < 256; off <<= 1) {
    int u = (t >= off) ? cur[t - off] : 0;
    __syncthreads();
    cur[t] += u;
    __syncthreads();
  }
  int excl = cur[t] - v;
  int node = nb0 + t;
  if (node < N_NODES) rs[node] = r0 + excl;
  if (b == 0 && t == 0) rs[N_NODES] = N_EDGES;
  __syncthreads();
  cur[t] = r0 + excl;
  __syncthreads();

  for (int e = r0 + t; e < r1; e += 256) {
    unsigned p = (unsigned)pairs[e];
    int pos = atomicAdd(&cur[p >> 24], 1);
    eidx[pos] = (int)(p & 0xFFFFFFu);
  }
}

// ---------------------------------------------------------------------------
// gather_h v4 = R8 v2 + (a) 4096 blocks (2x oversubscription) and
// (b) software-pipelined metadata: rs[n+1] prefetched before the Z-loads,
// eidx row for n+1 prefetched before the reduction tail. Per-node critical
// path collapses to just the Z-load latency.
// ---------------------------------------------------------------------------
__global__ __launch_bounds__(256) void gather_h(
    const __half* __restrict__ Uh, const __half* __restrict__ Zh,
    const int* __restrict__ rs, const int* __restrict__ eidx,
    const float* __restrict__ bneigh, const int* __restrict__ gids,
    int* __restrict__ hgbits) {
  int lane = threadIdx.x & 63;
  int wid  = (blockIdx.x * blockDim.x + threadIdx.x) >> 6;
  const int NW = (4096 * 256) >> 6;                 // 16384 waves
  const int per = (N_NODES + NW - 1) / NW;          // 7 nodes/wave
  int n0 = wid * per;
  int n1 = n0 + per; if (n1 > N_NODES) n1 = N_NODES;
  if (n0 >= n1) return;
  int fl  = lane & 15;
  int sub = lane >> 4;
  float4 b4 = *(const float4*)(bneigh + 4 * fl);

  int curg = gids[n0];
  float4 gmax = {0.f, 0.f, 0.f, 0.f};

  // prologue: metadata for the first node
  int r0 = rs[n0], r1 = rs[n0 + 1];
  int myid = (lane < r1 - r0) ? eidx[r0 + lane] : 0;

  for (int n = n0; n < n1; n++) {
    uint2 ur = *(const uint2*)(Uh + (size_t)n * F + 4 * fl);
    // early rs prefetch for n+1 (latency hidden by the Z-load loop below)
    int nr0 = 0, nr1 = 0;
    if (n + 1 < n1) { nr0 = rs[n + 1]; nr1 = rs[n + 2]; }

    float sx = 0.f, sy = 0.f, sz = 0.f, sw = 0.f;
    int deg = r1 - r0;
    int m0 = deg > 64 ? 64 : deg;
    for (int jj = 0; jj < m0; jj += 16) {
      int j0 = jj + sub;
      int s0 = __shfl(myid, j0);
      int s1 = __shfl(myid, j0 + 4);
      int s2 = __shfl(myid, j0 + 8);
      int s3 = __shfl(myid, j0 + 12);
      uint2 z0 = *(const uint2*)(Zh + (size_t)s0 * F + 4 * fl);
      uint2 z1 = *(const uint2*)(Zh + (size_t)s1 * F + 4 * fl);
      uint2 z2 = *(const uint2*)(Zh + (size_t)s2 * F + 4 * fl);
      uint2 z3 = *(const uint2*)(Zh + (size_t)s3 * F + 4 * fl);
      if (j0 < m0) {
        float2 f0 = __half22float2(*(__half2*)&z0.x);
        float2 f1 = __half22float2(*(__half2*)&z0.y);
        sx += f0.x; sy += f0.y; sz += f1.x; sw += f1.y;
      }
      if (j0 + 4 < m0) {
        float2 f0 = __half22float2(*(__half2*)&z1.x);
        float2 f1 = __half22float2(*(__half2*)&z1.y);
        sx += f0.x; sy += f0.y; sz += f1.x; sw += f1.y;
      }
      if (j0 + 8 < m0) {
        float2 f0 = __half22float2(*(__half2*)&z2.x);
        float2 f1 = __half22float2(*(__half2*)&z2.y);
        sx += f0.x; sy += f0.y; sz += f1.x; sw += f1.y;
      }
      if (j0 + 12 < m0) {
        float2 f0 = __half22float2(*(__half2*)&z3.x);
        float2 f1 = __half22float2(*(__half2*)&z3.y);
        sx += f0.x; sy += f0.y; sz += f1.x; sw += f1.y;
      }
    }
    // rare: degree > 64 (safety path, loads eidx inline)
    for (int base = r0 + 64; base < r1; base += 64) {
      int m = r1 - base; if (m > 64) m = 64;
      int myid2 = (lane < m) ? eidx[base + lane] : 0;
      for (int jj = 0; jj < m; jj += 16) {
        int j0 = jj + sub;
        int s0 = __shfl(myid2, j0);
        int s1 = __shfl(myid2, j0 + 4);
        int s2 = __shfl(myid2, j0 + 8);
        int s3 = __shfl(myid2, j0 + 12);
        uint2 z0 = *(const uint2*)(Zh + (size_t)s0 * F + 4 * fl);
        uint2 z1 = *(const uint2*)(Zh + (size_t)s1 * F + 4 * fl);
        uint2 z2 = *(const uint2*)(Zh + (size_t)s2 * F + 4 * fl);
        uint2 z3 = *(const uint2*)(Zh + (size_t)s3 * F + 4 * fl);
        if (j0 < m) {
          float2 f0 = __half22float2(*(__half2*)&z0.x);
          float2 f1 = __half22float2(*(__half2*)&z0.y);
          sx += f0.x; sy += f0.y; sz += f1.x; sw += f1.y;
        }
        if (j0 + 4 < m) {
          float2 f0 = __half22float2(*(__half2*)&z1.x);
          float2 f1 = __half22float2(*(__half2*)&z1.y);
          sx += f0.x; sy += f0.y; sz += f1.x; sw += f1.y;
        }
        if (j0 + 8 < m) {
          float2 f0 = __half22float2(*(__half2*)&z2.x);
          float2 f1 = __half22float2(*(__half2*)&z2.y);
          sx += f0.x; sy += f0.y; sz += f1.x; sw += f1.y;
        }
        if (j0 + 12 < m) {
          float2 f0 = __half22float2(*(__half2*)&z3.x);
          float2 f1 = __half22float2(*(__half2*)&z3.y);
          sx += f0.x; sy += f0.y; sz += f1.x; sw += f1.y;
        }
      }
    }

    // eidx prefetch for n+1 (latency hidden by the reduction tail below)
    int nmyid = 0;
    if (n + 1 < n1) nmyid = (lane < nr1 - nr0) ? eidx[nr0 + lane] : 0;

    sx += __shfl_xor(sx, 16); sy += __shfl_xor(sy, 16);
    sz += __shfl_xor(sz, 16); sw += __shfl_xor(sw, 16);
    sx += __shfl_xor(sx, 32); sy += __shfl_xor(sy, 32);
    sz += __shfl_xor(sz, 32); sw += __shfl_xor(sw, 32);
    float inv = 1.0f / fmaxf((float)deg, 1.0f);

    int g = gids[n];
    if (g != curg) {
      if (sub == 0) {
        int* hp = hgbits + (size_t)curg * F + 4 * fl;
        atomicMax(hp + 0, __float_as_int(gmax.x));
        atomicMax(hp + 1, __float_as_int(gmax.y));
        atomicMax(hp + 2, __float_as_int(gmax.z));
        atomicMax(hp + 3, __float_as_int(gmax.w));
      }
      curg = g; gmax = make_float4(0.f, 0.f, 0.f, 0.f);
    }

    float2 uf0 = __half22float2(*(__half2*)&ur.x);
    float2 uf1 = __half22float2(*(__half2*)&ur.y);
    gmax.x = fmaxf(gmax.x, fmaxf(uf0.x + sx * inv + b4.x, 0.f));
    gmax.y = fmaxf(gmax.y, fmaxf(uf0.y + sy * inv + b4.y, 0.f));
    gmax.z = fmaxf(gmax.z, fmaxf(uf1.x + sz * inv + b4.z, 0.f));
    gmax.w = fmaxf(gmax.w, fmaxf(uf1.y + sw * inv + b4.w, 0.f));

    r0 = nr0; r1 = nr1; myid = nmyid;   // rotate pipeline
  }
  if (sub == 0) {
    int* hp = hgbits + (size_t)curg * F + 4 * fl;
    atomicMax(hp + 0, __float_as_int(gmax.x));
    atomicMax(hp + 1, __float_as_int(gmax.y));
    atomicMax(hp + 2, __float_as_int(gmax.z));
    atomicMax(hp + 3, __float_as_int(gmax.w));
  }
}

// ---------------------------------------------------------------------------
// MLP head: weights staged in LDS once, 8 graphs per block.
// ---------------------------------------------------------------------------
#define GPB 8
__global__ __launch_bounds__(128) void mlp(
    const float* __restrict__ hg,
    const float* __restrict__ W1, const float* __restrict__ b1,
    const float* __restrict__ g1, const float* __restrict__ be1,
    const float* __restrict__ rm1, const float* __restrict__ rv1,
    const float* __restrict__ W2, const float* __restrict__ b2,
    const float* __restrict__ g2, const float* __restrict__ be2,
    const float* __restrict__ rm2, const float* __restrict__ rv2,
    const float* __restrict__ W3, const float* __restrict__ b3,
    float* __restrict__ out) {
  __shared__ float W1s[64 * 128];
  __shared__ float W2s[128 * 64];
  __shared__ float W3s[64];
  __shared__ float sc1[128], sh1[128], b1s[128];
  __shared__ float sc2[64],  sh2[64],  b2s[64];
  __shared__ float s0[64], s1[128], s2[64];
  int t = threadIdx.x;

  for (int i = t; i < 64 * 128; i += 128) W1s[i] = W1[i];
  for (int i = t; i < 128 * 64; i += 128) W2s[i] = W2[i];
  if (t < 64) W3s[t] = W3[t];
  {
    float iv = rsqrtf(rv1[t] + BN_EPS);
    float sc = g1[t] * iv;
    sc1[t] = sc; sh1[t] = be1[t] - rm1[t] * sc; b1s[t] = b1[t];
  }
  if (t < 64) {
    float iv = rsqrtf(rv2[t] + BN_EPS);
    float sc = g2[t] * iv;
    sc2[t] = sc; sh2[t] = be2[t] - rm2[t] * sc; b2s[t] = b2[t];
  }
  __syncthreads();

  for (int gg = 0; gg < GPB; gg++) {
    int g = blockIdx.x * GPB + gg;
    if (t < 64) s0[t] = hg[(size_t)g * F + t];
    __syncthreads();
    {
      float acc = b1s[t];
      for (int i = 0; i < 64; i++) acc += s0[i] * W1s[i * 128 + t];
      acc = fmaxf(acc, 0.0f);
      s1[t] = acc * sc1[t] + sh1[t];
    }
    __syncthreads();
    if (t < 64) {
      float acc = b2s[t];
      for (int i = 0; i < 128; i++) acc += s1[i] * W2s[i * 64 + t];
      acc = fmaxf(acc, 0.0f);
      s2[t] = acc * sc2[t] + sh2[t];
    }
    __syncthreads();
    if (t < 64) {
      float p = s2[t] * W3s[t];
      for (int off = 32; off > 0; off >>= 1) p += __shfl_down(p, off);
      if (t == 0) out[g] = p + b3[0];
    }
    __syncthreads();
  }
}

// ---------------------------------------------------------------------------
extern "C" void kernel_launch(void* const* d_in, const int* in_sizes, int n_in,
                              void* d_out, int out_size, void* d_ws, size_t ws_size,
                              hipStream_t stream) {
  const float* feats  = (const float*)d_in[0];
  const int*   src    = (const int*)d_in[1];
  const int*   dst    = (const int*)d_in[2];
  const int*   gids   = (const int*)d_in[3];
  const float* Wself  = (const float*)d_in[4];
  const float* Wneigh = (const float*)d_in[5];
  const float* bneigh = (const float*)d_in[6];
  const float* W1  = (const float*)d_in[7];
  const float* b1  = (const float*)d_in[8];
  const float* g1  = (const float*)d_in[9];
  const float* be1 = (const float*)d_in[10];
  const float* rm1 = (const float*)d_in[11];
  const float* rv1 = (const float*)d_in[12];
  const float* W2  = (const float*)d_in[13];
  const float* b2  = (const float*)d_in[14];
  const float* g2  = (const float*)d_in[15];
  const float* be2 = (const float*)d_in[16];
  const float* rm2 = (const float*)d_in[17];
  const float* rv2 = (const float*)d_in[18];
  const float* W3  = (const float*)d_in[19];
  const float* b3  = (const float*)d_in[20];

  // ws layout: Uh | Zh | rs | bstart | bcnt | done | hgbits | Ct | pairs | eidx
  __half* Uh   = (__half*)d_ws;                      // N_NODES*64 halves
  __half* Zh   = Uh + (size_t)N_NODES * F;           // N_NODES*64 halves
  int* rs      = (int*)(Zh + (size_t)N_NODES * F);   // N_NODES+1
  int* bstart  = rs + (N_NODES + 1);                 // NBUCK+1
  int* bcnt    = bstart + (NBUCK + 1);               // NBUCK
  int* done    = bcnt + NBUCK;                       // 1 (zeroed in prep)
  int* hgbits  = done + 1;                           // N_GRAPHS*F (zeroed in prep)
  int* Ct      = hgbits + (size_t)N_GRAPHS * F;      // NBLK*NBUCK
  int* pairs   = Ct + (size_t)NBLK * NBUCK;          // N_EDGES
  int* eidx    = pairs + N_EDGES;                    // N_EDGES

  prep<<<GEMM_BLOCKS + NBLK, 256, 0, stream>>>(feats, Wself, Wneigh, Uh, Zh,
                                               dst, Ct, hgbits, done);
  cscan2<<<NBUCK, NBLK, 0, stream>>>(Ct, bcnt, bstart, done);
  cscat<<<NBLK, 256, 0, stream>>>(src, dst, Ct, bstart, pairs);
  place<<<NBUCK, 256, 0, stream>>>(pairs, bstart, rs, eidx);
  gather_h<<<4096, 256, 0, stream>>>(Uh, Zh, rs, eidx, bneigh, gids, hgbits);
  mlp<<<N_GRAPHS / GPB, 128, 0, stream>>>((const float*)hgbits,
                                          W1, b1, g1, be1, rm1, rv1,
                                          W2, b2, g2, be2, rm2, rv2, W3, b3,
                                          (float*)d_out);
}

// Round 13
// 222.761 us; speedup vs baseline: 1.6999x; 1.3605x over previous
//
#include <hip/hip_runtime.h>
#include <hip/hip_fp16.h>

#define N_NODES  100000
#define N_EDGES  1200000
#define N_GRAPHS 1024
#define F        64
#define BN_EPS   1e-5f
#define NBUCK    ((N_NODES + 255) / 256)       // 391 buckets of 256 node IDs
#define NBLK     512                            // scatter chunks
#define CHUNK    ((N_EDGES + NBLK - 1) / NBLK)  // 2344 edges per chunk
#define MT       128                            // GEMM nodes per block
#define GEMM_BLOCKS ((N_NODES + MT - 1) / MT)   // 782

// ---------------------------------------------------------------------------
// prep: fused [gemm_uz | chist]. Blocks [0,GEMM_BLOCKS) do the dense GEMM
// Uh = feats@Wself, Zh = feats@Wneigh (fp16 out); the rest histogram dst
// buckets into Ct and zero hgbits.
// ---------------------------------------------------------------------------
__global__ __launch_bounds__(256) void prep(
    const float* __restrict__ feats, const float* __restrict__ Wself,
    const float* __restrict__ Wneigh, __half* __restrict__ Uh,
    __half* __restrict__ Zh, const int* __restrict__ dst,
    int* __restrict__ Ct, int* __restrict__ hgbits) {
  __shared__ __align__(16) char smraw[MT * 65 * 4 + 64 * 128 * 4];
  int t = threadIdx.x;

  if (blockIdx.x >= GEMM_BLOCKS) {
    int* lh = (int*)smraw;
    int b = blockIdx.x - GEMM_BLOCKS;
    int zidx = b * 256 + t;
    if (zidx < N_GRAPHS * F) hgbits[zidx] = 0;
    for (int i = t; i < NBUCK; i += 256) lh[i] = 0;
    __syncthreads();
    int e0 = b * CHUNK, e1 = e0 + CHUNK;
    if (e1 > N_EDGES) e1 = N_EDGES;
    for (int e = e0 + t; e < e1; e += 256) atomicAdd(&lh[dst[e] >> 8], 1);
    __syncthreads();
    for (int i = t; i < NBUCK; i += 256) Ct[(size_t)b * NBUCK + i] = lh[i];
    return;
  }

  float* As = (float*)smraw;                   // MT x 65
  float* Ws = (float*)(smraw + MT * 65 * 4);   // 64 x 128
  int mbase = blockIdx.x * MT;

  for (int i = t; i < 64 * 128; i += 256) {
    int k = i >> 7, j = i & 127;
    Ws[i] = (j < 64) ? Wself[k * 64 + j] : Wneigh[k * 64 + (j - 64)];
  }
#pragma unroll
  for (int s = 0; s < 8; s++) {
    int idx = (s * 256 + t) * 4;
    int m = idx >> 6, k = idx & 63;
    int gm = mbase + m;
    float4 v = (gm < N_NODES) ? *(const float4*)(feats + (size_t)gm * F + k)
                              : make_float4(0.f, 0.f, 0.f, 0.f);
    float* d = As + m * 65 + k;
    d[0] = v.x; d[1] = v.y; d[2] = v.z; d[3] = v.w;
  }
  __syncthreads();

  int wave = t >> 6, lane = t & 63;
  int jq = lane & 3, nq = lane >> 2;
  int half = wave & 1;
  int mb = (wave >> 1) * 64 + 4 * nq;
  int joff = half * 64 + jq * 16;

  float acc[4][16];
#pragma unroll
  for (int i = 0; i < 4; i++)
#pragma unroll
    for (int c = 0; c < 16; c++) acc[i][c] = 0.f;

#pragma unroll 4
  for (int k = 0; k < 64; k++) {
    float a0 = As[(mb + 0) * 65 + k];
    float a1 = As[(mb + 1) * 65 + k];
    float a2 = As[(mb + 2) * 65 + k];
    float a3 = As[(mb + 3) * 65 + k];
    const float4* wr = (const float4*)(Ws + k * 128 + joff);
    float4 w4[4];
    w4[0] = wr[0]; w4[1] = wr[1]; w4[2] = wr[2]; w4[3] = wr[3];
    const float* w = (const float*)w4;
#pragma unroll
    for (int c = 0; c < 16; c++) {
      float wv = w[c];
      acc[0][c] += a0 * wv;
      acc[1][c] += a1 * wv;
      acc[2][c] += a2 * wv;
      acc[3][c] += a3 * wv;
    }
  }

  __half* outp = half ? Zh : Uh;
  int jbase = jq * 16;
#pragma unroll
  for (int i = 0; i < 4; i++) {
    int gm = mbase + mb + i;
    if (gm < N_NODES) {
#pragma unroll
      for (int c4 = 0; c4 < 4; c4++) {
        union { __half h[4]; uint2 u; } pk;
        pk.h[0] = __float2half_rn(acc[i][c4 * 4 + 0]);
        pk.h[1] = __float2half_rn(acc[i][c4 * 4 + 1]);
        pk.h[2] = __float2half_rn(acc[i][c4 * 4 + 2]);
        pk.h[3] = __float2half_rn(acc[i][c4 * 4 + 3]);
        *(uint2*)(outp + (size_t)gm * F + jbase + c4 * 4) = pk.u;
      }
    }
  }
}

// ---------------------------------------------------------------------------
// cscan: per-bucket scan over chunk counts (R8 proven — no fence/flags).
// ---------------------------------------------------------------------------
__global__ __launch_bounds__(NBLK) void cscan(int* __restrict__ Ct,
                                              int* __restrict__ bcnt) {
  __shared__ int s[NBLK];
  int i = blockIdx.x, t = threadIdx.x;
  int v = Ct[(size_t)t * NBUCK + i];
  s[t] = v;
  __syncthreads();
  for (int off = 1; off < NBLK; off <<= 1) {
    int u = (t >= off) ? s[t - off] : 0;
    __syncthreads();
    s[t] += u;
    __syncthreads();
  }
  Ct[(size_t)t * NBUCK + i] = s[t] - v;
  if (t == NBLK - 1) bcnt[i] = s[NBLK - 1];
}

// ---------------------------------------------------------------------------
// bscan: scan 391 bucket totals -> bstart (R8 proven).
// ---------------------------------------------------------------------------
__global__ __launch_bounds__(512) void bscan(const int* __restrict__ bcnt,
                                             int* __restrict__ bstart) {
  __shared__ int s[512];
  int t = threadIdx.x;
  int v = (t < NBUCK) ? bcnt[t] : 0;
  s[t] = v;
  __syncthreads();
  for (int off = 1; off < 512; off <<= 1) {
    int u = (t >= off) ? s[t - off] : 0;
    __syncthreads();
    s[t] += u;
    __syncthreads();
  }
  if (t < NBUCK) bstart[t] = s[t] - v;
  if (t == 0) bstart[NBUCK] = N_EDGES;
}

// ---------------------------------------------------------------------------
// cscat: deterministic scatter of packed (local_dst<<24 | src) (proven).
// ---------------------------------------------------------------------------
__global__ __launch_bounds__(256) void cscat(const int* __restrict__ src,
                                             const int* __restrict__ dst,
                                             const int* __restrict__ Ct,
                                             const int* __restrict__ bstart,
                                             int* __restrict__ pairs) {
  __shared__ int cur[NBUCK];
  int b = blockIdx.x, t = threadIdx.x;
  for (int i = t; i < NBUCK; i += 256)
    cur[i] = bstart[i] + Ct[(size_t)b * NBUCK + i];
  __syncthreads();
  int e0 = b * CHUNK, e1 = e0 + CHUNK;
  if (e1 > N_EDGES) e1 = N_EDGES;
  for (int e = e0 + t; e < e1; e += 256) {
    int d = dst[e];
    int pos = atomicAdd(&cur[d >> 8], 1);
    pairs[pos] = (int)((((unsigned)d & 255u) << 24) | (unsigned)src[e]);
  }
}

// ---------------------------------------------------------------------------
// place: per-bucket rs + sorted eidx (proven).
// ---------------------------------------------------------------------------
__global__ __launch_bounds__(256) void place(const int* __restrict__ pairs,
                                             const int* __restrict__ bstart,
                                             int* __restrict__ rs,
                                             int* __restrict__ eidx) {
  __shared__ int lh[256];
  __shared__ int cur[256];
  int b = blockIdx.x, t = threadIdx.x;
  int nb0 = b << 8;
  int r0 = bstart[b], r1 = bstart[b + 1];

  lh[t] = 0;
  __syncthreads();
  for (int e = r0 + t; e < r1; e += 256)
    atomicAdd(&lh[((unsigned)pairs[e]) >> 24], 1);
  __syncthreads();

  int v = lh[t];
  cur[t] = v;
  __syncthreads();
  for (int off = 1; off < 256; off <<= 1) {
    int u = (t >= off) ? cur[t - off] : 0;
    __syncthreads();
    cur[t] += u;
    __syncthreads();
  }
  int excl = cur[t] - v;
  int node = nb0 + t;
  if (node < N_NODES) rs[node] = r0 + excl;
  if (b == 0 && t == 0) rs[N_NODES] = N_EDGES;
  __syncthreads();
  cur[t] = r0 + excl;
  __syncthreads();

  for (int e = r0 + t; e < r1; e += 256) {
    unsigned p = (unsigned)pairs[e];
    int pos = atomicAdd(&cur[p >> 24], 1);
    eidx[pos] = (int)(p & 0xFFFFFFu);
  }
}

// ---------------------------------------------------------------------------
// gather_h v4: R8 v2 + 4096 blocks (2x oversubscription) + software-pipelined
// rs/eidx metadata prefetch (neutral-to-positive per R12 residual analysis).
// ---------------------------------------------------------------------------
__global__ __launch_bounds__(256) void gather_h(
    const __half* __restrict__ Uh, const __half* __restrict__ Zh,
    const int* __restrict__ rs, const int* __restrict__ eidx,
    const float* __restrict__ bneigh, const int* __restrict__ gids,
    int* __restrict__ hgbits) {
  int lane = threadIdx.x & 63;
  int wid  = (blockIdx.x * blockDim.x + threadIdx.x) >> 6;
  const int NW = (4096 * 256) >> 6;                 // 16384 waves
  const int per = (N_NODES + NW - 1) / NW;          // 7 nodes/wave
  int n0 = wid * per;
  int n1 = n0 + per; if (n1 > N_NODES) n1 = N_NODES;
  if (n0 >= n1) return;
  int fl  = lane & 15;
  int sub = lane >> 4;
  float4 b4 = *(const float4*)(bneigh + 4 * fl);

  int curg = gids[n0];
  float4 gmax = {0.f, 0.f, 0.f, 0.f};

  int r0 = rs[n0], r1 = rs[n0 + 1];
  int myid = (lane < r1 - r0) ? eidx[r0 + lane] : 0;

  for (int n = n0; n < n1; n++) {
    uint2 ur = *(const uint2*)(Uh + (size_t)n * F + 4 * fl);
    int nr0 = 0, nr1 = 0;
    if (n + 1 < n1) { nr0 = rs[n + 1]; nr1 = rs[n + 2]; }

    float sx = 0.f, sy = 0.f, sz = 0.f, sw = 0.f;
    int deg = r1 - r0;
    int m0 = deg > 64 ? 64 : deg;
    for (int jj = 0; jj < m0; jj += 16) {
      int j0 = jj + sub;
      int s0 = __shfl(myid, j0);
      int s1 = __shfl(myid, j0 + 4);
      int s2 = __shfl(myid, j0 + 8);
      int s3 = __shfl(myid, j0 + 12);
      uint2 z0 = *(const uint2*)(Zh + (size_t)s0 * F + 4 * fl);
      uint2 z1 = *(const uint2*)(Zh + (size_t)s1 * F + 4 * fl);
      uint2 z2 = *(const uint2*)(Zh + (size_t)s2 * F + 4 * fl);
      uint2 z3 = *(const uint2*)(Zh + (size_t)s3 * F + 4 * fl);
      if (j0 < m0) {
        float2 f0 = __half22float2(*(__half2*)&z0.x);
        float2 f1 = __half22float2(*(__half2*)&z0.y);
        sx += f0.x; sy += f0.y; sz += f1.x; sw += f1.y;
      }
      if (j0 + 4 < m0) {
        float2 f0 = __half22float2(*(__half2*)&z1.x);
        float2 f1 = __half22float2(*(__half2*)&z1.y);
        sx += f0.x; sy += f0.y; sz += f1.x; sw += f1.y;
      }
      if (j0 + 8 < m0) {
        float2 f0 = __half22float2(*(__half2*)&z2.x);
        float2 f1 = __half22float2(*(__half2*)&z2.y);
        sx += f0.x; sy += f0.y; sz += f1.x; sw += f1.y;
      }
      if (j0 + 12 < m0) {
        float2 f0 = __half22float2(*(__half2*)&z3.x);
        float2 f1 = __half22float2(*(__half2*)&z3.y);
        sx += f0.x; sy += f0.y; sz += f1.x; sw += f1.y;
      }
    }
    for (int base = r0 + 64; base < r1; base += 64) {   // rare deg>64 path
      int m = r1 - base; if (m > 64) m = 64;
      int myid2 = (lane < m) ? eidx[base + lane] : 0;
      for (int jj = 0; jj < m; jj += 16) {
        int j0 = jj + sub;
        int s0 = __shfl(myid2, j0);
        int s1 = __shfl(myid2, j0 + 4);
        int s2 = __shfl(myid2, j0 + 8);
        int s3 = __shfl(myid2, j0 + 12);
        uint2 z0 = *(const uint2*)(Zh + (size_t)s0 * F + 4 * fl);
        uint2 z1 = *(const uint2*)(Zh + (size_t)s1 * F + 4 * fl);
        uint2 z2 = *(const uint2*)(Zh + (size_t)s2 * F + 4 * fl);
        uint2 z3 = *(const uint2*)(Zh + (size_t)s3 * F + 4 * fl);
        if (j0 < m) {
          float2 f0 = __half22float2(*(__half2*)&z0.x);
          float2 f1 = __half22float2(*(__half2*)&z0.y);
          sx += f0.x; sy += f0.y; sz += f1.x; sw += f1.y;
        }
        if (j0 + 4 < m) {
          float2 f0 = __half22float2(*(__half2*)&z1.x);
          float2 f1 = __half22float2(*(__half2*)&z1.y);
          sx += f0.x; sy += f0.y; sz += f1.x; sw += f1.y;
        }
        if (j0 + 8 < m) {
          float2 f0 = __half22float2(*(__half2*)&z2.x);
          float2 f1 = __half22float2(*(__half2*)&z2.y);
          sx += f0.x; sy += f0.y; sz += f1.x; sw += f1.y;
        }
        if (j0 + 12 < m) {
          float2 f0 = __half22float2(*(__half2*)&z3.x);
          float2 f1 = __half22float2(*(__half2*)&z3.y);
          sx += f0.x; sy += f0.y; sz += f1.x; sw += f1.y;
        }
      }
    }

    int nmyid = 0;
    if (n + 1 < n1) nmyid = (lane < nr1 - nr0) ? eidx[nr0 + lane] : 0;

    sx += __shfl_xor(sx, 16); sy += __shfl_xor(sy, 16);
    sz += __shfl_xor(sz, 16); sw += __shfl_xor(sw, 16);
    sx += __shfl_xor(sx, 32); sy += __shfl_xor(sy, 32);
    sz += __shfl_xor(sz, 32); sw += __shfl_xor(sw, 32);
    float inv = 1.0f / fmaxf((float)deg, 1.0f);

    int g = gids[n];
    if (g != curg) {
      if (sub == 0) {
        int* hp = hgbits + (size_t)curg * F + 4 * fl;
        atomicMax(hp + 0, __float_as_int(gmax.x));
        atomicMax(hp + 1, __float_as_int(gmax.y));
        atomicMax(hp + 2, __float_as_int(gmax.z));
        atomicMax(hp + 3, __float_as_int(gmax.w));
      }
      curg = g; gmax = make_float4(0.f, 0.f, 0.f, 0.f);
    }

    float2 uf0 = __half22float2(*(__half2*)&ur.x);
    float2 uf1 = __half22float2(*(__half2*)&ur.y);
    gmax.x = fmaxf(gmax.x, fmaxf(uf0.x + sx * inv + b4.x, 0.f));
    gmax.y = fmaxf(gmax.y, fmaxf(uf0.y + sy * inv + b4.y, 0.f));
    gmax.z = fmaxf(gmax.z, fmaxf(uf1.x + sz * inv + b4.z, 0.f));
    gmax.w = fmaxf(gmax.w, fmaxf(uf1.y + sw * inv + b4.w, 0.f));

    r0 = nr0; r1 = nr1; myid = nmyid;
  }
  if (sub == 0) {
    int* hp = hgbits + (size_t)curg * F + 4 * fl;
    atomicMax(hp + 0, __float_as_int(gmax.x));
    atomicMax(hp + 1, __float_as_int(gmax.y));
    atomicMax(hp + 2, __float_as_int(gmax.z));
    atomicMax(hp + 3, __float_as_int(gmax.w));
  }
}

// ---------------------------------------------------------------------------
// MLP head: weights staged in LDS once, 8 graphs per block.
// ---------------------------------------------------------------------------
#define GPB 8
__global__ __launch_bounds__(128) void mlp(
    const float* __restrict__ hg,
    const float* __restrict__ W1, const float* __restrict__ b1,
    const float* __restrict__ g1, const float* __restrict__ be1,
    const float* __restrict__ rm1, const float* __restrict__ rv1,
    const float* __restrict__ W2, const float* __restrict__ b2,
    const float* __restrict__ g2, const float* __restrict__ be2,
    const float* __restrict__ rm2, const float* __restrict__ rv2,
    const float* __restrict__ W3, const float* __restrict__ b3,
    float* __restrict__ out) {
  __shared__ float W1s[64 * 128];
  __shared__ float W2s[128 * 64];
  __shared__ float W3s[64];
  __shared__ float sc1[128], sh1[128], b1s[128];
  __shared__ float sc2[64],  sh2[64],  b2s[64];
  __shared__ float s0[64], s1[128], s2[64];
  int t = threadIdx.x;

  for (int i = t; i < 64 * 128; i += 128) W1s[i] = W1[i];
  for (int i = t; i < 128 * 64; i += 128) W2s[i] = W2[i];
  if (t < 64) W3s[t] = W3[t];
  {
    float iv = rsqrtf(rv1[t] + BN_EPS);
    float sc = g1[t] * iv;
    sc1[t] = sc; sh1[t] = be1[t] - rm1[t] * sc; b1s[t] = b1[t];
  }
  if (t < 64) {
    float iv = rsqrtf(rv2[t] + BN_EPS);
    float sc = g2[t] * iv;
    sc2[t] = sc; sh2[t] = be2[t] - rm2[t] * sc; b2s[t] = b2[t];
  }
  __syncthreads();

  for (int gg = 0; gg < GPB; gg++) {
    int g = blockIdx.x * GPB + gg;
    if (t < 64) s0[t] = hg[(size_t)g * F + t];
    __syncthreads();
    {
      float acc = b1s[t];
      for (int i = 0; i < 64; i++) acc += s0[i] * W1s[i * 128 + t];
      acc = fmaxf(acc, 0.0f);
      s1[t] = acc * sc1[t] + sh1[t];
    }
    __syncthreads();
    if (t < 64) {
      float acc = b2s[t];
      for (int i = 0; i < 128; i++) acc += s1[i] * W2s[i * 64 + t];
      acc = fmaxf(acc, 0.0f);
      s2[t] = acc * sc2[t] + sh2[t];
    }
    __syncthreads();
    if (t < 64) {
      float p = s2[t] * W3s[t];
      for (int off = 32; off > 0; off >>= 1) p += __shfl_down(p, off);
      if (t == 0) out[g] = p + b3[0];
    }
    __syncthreads();
  }
}

// ---------------------------------------------------------------------------
extern "C" void kernel_launch(void* const* d_in, const int* in_sizes, int n_in,
                              void* d_out, int out_size, void* d_ws, size_t ws_size,
                              hipStream_t stream) {
  const float* feats  = (const float*)d_in[0];
  const int*   src    = (const int*)d_in[1];
  const int*   dst    = (const int*)d_in[2];
  const int*   gids   = (const int*)d_in[3];
  const float* Wself  = (const float*)d_in[4];
  const float* Wneigh = (const float*)d_in[5];
  const float* bneigh = (const float*)d_in[6];
  const float* W1  = (const float*)d_in[7];
  const float* b1  = (const float*)d_in[8];
  const float* g1  = (const float*)d_in[9];
  const float* be1 = (const float*)d_in[10];
  const float* rm1 = (const float*)d_in[11];
  const float* rv1 = (const float*)d_in[12];
  const float* W2  = (const float*)d_in[13];
  const float* b2  = (const float*)d_in[14];
  const float* g2  = (const float*)d_in[15];
  const float* be2 = (const float*)d_in[16];
  const float* rm2 = (const float*)d_in[17];
  const float* rv2 = (const float*)d_in[18];
  const float* W3  = (const float*)d_in[19];
  const float* b3  = (const float*)d_in[20];

  // ws layout: Uh | Zh | rs | bstart | bcnt | hgbits | Ct | pairs | eidx
  __half* Uh   = (__half*)d_ws;                      // N_NODES*64 halves
  __half* Zh   = Uh + (size_t)N_NODES * F;           // N_NODES*64 halves
  int* rs      = (int*)(Zh + (size_t)N_NODES * F);   // N_NODES+1
  int* bstart  = rs + (N_NODES + 1);                 // NBUCK+1
  int* bcnt    = bstart + (NBUCK + 1);               // NBUCK
  int* hgbits  = bcnt + NBUCK;                       // N_GRAPHS*F (zeroed in prep)
  int* Ct      = hgbits + (size_t)N_GRAPHS * F;      // NBLK*NBUCK
  int* pairs   = Ct + (size_t)NBLK * NBUCK;          // N_EDGES
  int* eidx    = pairs + N_EDGES;                    // N_EDGES

  prep<<<GEMM_BLOCKS + NBLK, 256, 0, stream>>>(feats, Wself, Wneigh, Uh, Zh,
                                               dst, Ct, hgbits);
  cscan<<<NBUCK, NBLK, 0, stream>>>(Ct, bcnt);
  bscan<<<1, 512, 0, stream>>>(bcnt, bstart);
  cscat<<<NBLK, 256, 0, stream>>>(src, dst, Ct, bstart, pairs);
  place<<<NBUCK, 256, 0, stream>>>(pairs, bstart, rs, eidx);
  gather_h<<<4096, 256, 0, stream>>>(Uh, Zh, rs, eidx, bneigh, gids, hgbits);
  mlp<<<N_GRAPHS / GPB, 128, 0, stream>>>((const float*)hgbits,
                                          W1, b1, g1, be1, rm1, rv1,
                                          W2, b2, g2, be2, rm2, rv2, W3, b3,
                                          (float*)d_out);
}